// Round 15
// baseline (242.008 us; speedup 1.0000x reference)
//
#include <hip/hip_runtime.h>

typedef __attribute__((ext_vector_type(8))) short short8;
typedef __attribute__((ext_vector_type(4))) float f32x4;

// Problem dims
#define BDIM 4096
#define INDIM 1024
#define HDIM 2048
#define KDIM 3072   // IN + H
#define NDIM 8192   // 4*H
#define OUT_HALF 8388608  // 4096*2048
#define NKT 96      // K-tiles of 32
#define ACHUNKS 1572864   // A chunks of 8 bf16
#define WTHREADS 786432   // W pack threads (8192 cols x 96 k-tiles)

__device__ __forceinline__ unsigned short f2bf(float f) {
  unsigned u = __float_as_uint(f);
  u += 0x7FFFu + ((u >> 16) & 1u);
  return (unsigned short)(u >> 16);
}

__device__ __forceinline__ float sigmoidf_(float x) {
  return 1.0f / (1.0f + __expf(-x));
}

// Merged pack:
//  A = [x|h] bf16 row-major [4096][3072].
//  W' = gate-interleaved bf16 in FRAG-MAJOR layout: 16B chunk index
//    (tn*96+T)*1024 + wc*256 + ni*64 + fq*16 + fr
//  holds B[col' = tn*256+wc*64+ni*16+fr][k = T*32+fq*8 .. +8], so a wave's
//  B-frag global load (lane = fq*16+fr) is fully coalesced (1KB).
//  bias[n'] = b_ih + b_hh.
__global__ __launch_bounds__(256) void pack_all(
    const float* __restrict__ x, const float* __restrict__ hh,
    const float* __restrict__ w_ih, const float* __restrict__ w_hh,
    const float* __restrict__ b_ih, const float* __restrict__ b_hh,
    unsigned short* __restrict__ A, unsigned short* __restrict__ W,
    float* __restrict__ bias) {
  int idx = blockIdx.x * 256 + threadIdx.x;
  if (idx < ACHUNKS) {
    int m = idx / 384;
    int k0 = (idx - m * 384) * 8;
    const float* src = (k0 < INDIM) ? (x + (size_t)m * INDIM + k0)
                                    : (hh + (size_t)m * HDIM + (k0 - INDIM));
    float4 lo = ((const float4*)src)[0];
    float4 hi = ((const float4*)src)[1];
    union { unsigned short us[8]; uint4 v; } o;
    o.us[0] = f2bf(lo.x); o.us[1] = f2bf(lo.y); o.us[2] = f2bf(lo.z); o.us[3] = f2bf(lo.w);
    o.us[4] = f2bf(hi.x); o.us[5] = f2bf(hi.y); o.us[6] = f2bf(hi.z); o.us[7] = f2bf(hi.w);
    *(uint4*)(A + (size_t)m * KDIM + k0) = o.v;
  } else {
    int widx = idx - ACHUNKS;
    if (widx >= WTHREADS) return;
    // widx -> (tn, T, q); q = wc*64 + ni*16 + fr; col' = tn*256 + q.
    int tn = widx / 24576;            // 96*256
    int rr = widx - tn * 24576;
    int T = rr >> 8;                  // 0..95
    int q = rr & 255;
    int np = tn * 256 + q;            // col' in [0,8192)
    int j = np >> 2;
    int g = np & 3;
    int n = g * HDIM + j;
    int k0 = T * 32;
    const float* src = (k0 < INDIM) ? (w_ih + (size_t)n * INDIM + k0)
                                    : (w_hh + (size_t)n * HDIM + (k0 - INDIM));
    // read 32 f32, convert, write 4 x 16B at frag-major positions (fq 0..3)
    size_t cbase = ((size_t)(tn * 96 + T) << 10) + (size_t)(q >> 4) * 64 * 4 /*wc*256? no*/;
    // chunk = (tn*96+T)*1024 + wc*256 + ni*64 + fq*16 + fr, with q = wc*64+ni*16+fr:
    int wc = q >> 6, ni = (q >> 4) & 3, fr = q & 15;
    size_t chunk0 = ((size_t)(tn * 96 + T) << 10) + wc * 256 + ni * 64 + fr;
#pragma unroll
    for (int fq = 0; fq < 4; ++fq) {
      float4 lo = ((const float4*)(src + fq * 8))[0];
      float4 hi = ((const float4*)(src + fq * 8))[1];
      union { unsigned short us[8]; uint4 v; } o;
      o.us[0] = f2bf(lo.x); o.us[1] = f2bf(lo.y); o.us[2] = f2bf(lo.z); o.us[3] = f2bf(lo.w);
      o.us[4] = f2bf(hi.x); o.us[5] = f2bf(hi.y); o.us[6] = f2bf(hi.z); o.us[7] = f2bf(hi.w);
      *(uint4*)(W + ((chunk0 + fq * 16) << 3)) = o.v;
    }
    if (T == 0) bias[np] = b_ih[n] + b_hh[n];
  }
}

__device__ __forceinline__ void gload_lds16(const void* g, void* l) {
  __builtin_amdgcn_global_load_lds(
      (const __attribute__((address_space(1))) void*)g,
      (__attribute__((address_space(3))) void*)l, 16, 0, 0);
}

#define SB0 __builtin_amdgcn_sched_barrier(0)

// 256x256 tile, BK=32, 8 waves (2Mx4N). A staged in 4-deep LDS ring
// (4 x 16KiB, row-pair XOR swizzle T2); B read as coalesced per-wave frag
// loads from frag-major W' (L2-resident slab) into bfA/bfB ping-pong regs,
// 2 bodies ahead. R10's 1-barrier-per-K-tile rhythm + setprio.
// vmcnt invariant: B(T) issued after A(T+1), so the auto-wait before
// MFMA-A(T) drains A(T+1); explicit vmcnt(8) keeps {A(T+2),B(T+1),A(T+3)}.
__global__ __launch_bounds__(512, 2) void lstm_gemm(
    const unsigned short* __restrict__ A,
    const unsigned short* __restrict__ W,
    const float* __restrict__ bias,
    const float* __restrict__ c,
    float* __restrict__ out) {
  extern __shared__ char smem[];  // 65536 bytes: ring 4x16KiB

  const int tid = threadIdx.x;
  const int lane = tid & 63;
  const int wid = tid >> 6;

  // XCD swizzle: xcd owns 2 tm slabs; tn sweeps slowest. Bijective over 512.
  const int bid = blockIdx.x;
  const int local = bid >> 3;
  const int tm = (bid & 7) * 2 + (local & 1);   // 0..15
  const int tn = local >> 1;                    // 0..31

  // ---- A staging source decode (inverse swizzle, rule #21; R10-identical) ----
  int rowA0, clA0, rowA1, clA1;
  {
    int P0 = wid * 1024 + lane * 16;
    int P1 = 8192 + wid * 1024 + lane * 16;
    int r2, cp, cg;
    r2 = P0 >> 7; cp = (P0 >> 4) & 7; cg = cp ^ (r2 & 7);
    rowA0 = r2 * 2 + (cg >> 2); clA0 = cg & 3;
    r2 = P1 >> 7; cp = (P1 >> 4) & 7; cg = cp ^ (r2 & 7);
    rowA1 = r2 * 2 + (cg >> 2); clA1 = cg & 3;
  }
  const unsigned short* gA0 = A + (size_t)(tm * 256 + rowA0) * KDIM + clA0 * 8;
  const unsigned short* gA1 = A + (size_t)(tm * 256 + rowA1) * KDIM + clA1 * 8;
  const int ldA0 = wid * 1024;
  const int ldA1 = 8192 + wid * 1024;

  // ---- ds_read per-lane constants (swizzled A frags) ----
  const int fr = lane & 15;
  const int fq = lane >> 4;
  const int wr = wid >> 2;    // 0..1 (M half)
  const int wc = wid & 3;     // 0..3 (N quarter)
  const int frh = fr >> 1;
  const int clA = (((fr & 1) << 2) | fq) ^ frh;
  const int aconst = wr * 8192 + frh * 128 + clA * 16;   // + mi*1024

  // ---- B frag-major per-lane global pointer ----
  // chunk(T, ni) = (tn*96+T)*1024 + wc*256 + ni*64 + lane; bytes = chunk*16.
  const char* gBlane = (const char*)W +
      (((size_t)(tn * 96) << 10) + (size_t)wc * 256 + lane) * 16;

  f32x4 acc[8][4] = {};
  short8 af[4], ag[4], bfA[4], bfB[4];

  // ---- prologue: stage A(0,1,2); load B(0)->bfA, B(1)->bfB ----
#pragma unroll
  for (int tt = 0; tt < 3; ++tt) {
    char* lb = smem + tt * 16384;
    gload_lds16(gA0, lb + ldA0);
    gload_lds16(gA1, lb + ldA1);
    gA0 += 32; gA1 += 32;
  }
#pragma unroll
  for (int ni = 0; ni < 4; ++ni)
    bfA[ni] = *(const short8*)(gBlane + ni * 1024);
#pragma unroll
  for (int ni = 0; ni < 4; ++ni)
    bfB[ni] = *(const short8*)(gBlane + 16384 + ni * 1024);
  asm volatile("s_waitcnt vmcnt(12)" ::: "memory");   // A(0) landed
  __builtin_amdgcn_s_barrier(); SB0;
#pragma unroll
  for (int mi = 0; mi < 4; ++mi)
    af[mi] = *(const short8*)(smem + aconst + mi * 1024);

// Body T. Entry: af(T) issued; BFC holds B(T) (landing; auto-wait drains it
// and, being older, A(T+1) too); BFN holds B(T+1) in flight; A(T+1),A(T+2)
// staged. Tail loads B(T+2) into BFC (freed by MFMA-B).
#define TILE_BODY(T, STAGE_, PREFA_, LOADB_, BFC)                            \
  do {                                                                       \
    const char* rb = smem + ((T) & 3) * 16384;                               \
    const char* rbn = smem + (((T) + 1) & 3) * 16384;                        \
    char* lb = smem + (((T) + 3) & 3) * 16384;                               \
    if (STAGE_) {                                                            \
      gload_lds16(gA0, lb + ldA0);                                           \
      gload_lds16(gA1, lb + ldA1);                                           \
      gA0 += 32; gA1 += 32;                                                  \
    }                                                                        \
    _Pragma("unroll")                                                        \
    for (int mi = 0; mi < 4; ++mi)                                           \
      ag[mi] = *(const short8*)(rb + aconst + (mi + 4) * 1024);              \
    SB0;                                                                     \
    __builtin_amdgcn_s_setprio(1);                                           \
    _Pragma("unroll")                                                        \
    for (int mi = 0; mi < 4; ++mi)                                           \
      _Pragma("unroll")                                                      \
      for (int ni = 0; ni < 4; ++ni)                                         \
        acc[mi][ni] = __builtin_amdgcn_mfma_f32_16x16x32_bf16(               \
            af[mi], BFC[ni], acc[mi][ni], 0, 0, 0);                          \
    __builtin_amdgcn_s_setprio(0);                                           \
    asm volatile("s_waitcnt vmcnt(8)" ::: "memory");                         \
    asm volatile("s_waitcnt lgkmcnt(0)" ::: "memory");                       \
    __builtin_amdgcn_s_barrier(); SB0;                                       \
    if (PREFA_) {                                                            \
      _Pragma("unroll")                                                      \
      for (int mi = 0; mi < 4; ++mi)                                         \
        af[mi] = *(const short8*)(rbn + aconst + mi * 1024);                 \
    }                                                                        \
    SB0;                                                                     \
    __builtin_amdgcn_s_setprio(1);                                           \
    _Pragma("unroll")                                                        \
    for (int mi = 0; mi < 4; ++mi)                                           \
      _Pragma("unroll")                                                      \
      for (int ni = 0; ni < 4; ++ni)                                         \
        acc[mi + 4][ni] = __builtin_amdgcn_mfma_f32_16x16x32_bf16(           \
            ag[mi], BFC[ni], acc[mi + 4][ni], 0, 0, 0);                      \
    __builtin_amdgcn_s_setprio(0);                                           \
    if (LOADB_) {                                                            \
      _Pragma("unroll")                                                      \
      for (int ni = 0; ni < 4; ++ni)                                         \
        BFC[ni] = *(const short8*)(gBlane + (size_t)((T) + 2) * 16384 +      \
                                   ni * 1024);                               \
    }                                                                        \
    SB0;                                                                     \
  } while (0)

  for (int t = 0; t < 92; t += 2) {
    TILE_BODY(t,     true, true, true, bfA);
    TILE_BODY(t + 1, true, true, true, bfB);
  }
  TILE_BODY(92, true,  true,  true,  bfA);
  TILE_BODY(93, false, true,  true,  bfB);
  TILE_BODY(94, false, true,  false, bfA);
  TILE_BODY(95, false, false, false, bfB);
#undef TILE_BODY

  // ---- fused LSTM epilogue ----
  // Wave-private LDS bounce, stride 68 floats (8 x 4608 = 36864 B). Ring
  // reads in this region ended >= 2 barriers ago (body 94's ag from buf2,
  // drained by its lgkm0); body 95 reads only buf3 (48-64KiB).
  const int jw = fr;
  const int jg = tn * 64 + wc * 16 + jw;   // global j in [0,2048)
  const f32x4 bi = *(const f32x4*)(bias + tn * 256 + wc * 64 + jw * 4);
  float* ep = (float*)smem + wid * 1152;

#pragma unroll
  for (int mi = 0; mi < 8; ++mi) {
#pragma unroll
    for (int ni = 0; ni < 4; ++ni)
#pragma unroll
      for (int r = 0; r < 4; ++r)
        ep[(fq * 4 + r) * 68 + ni * 16 + fr] = acc[mi][ni][r];
    asm volatile("s_waitcnt lgkmcnt(0)" ::: "memory");
#pragma unroll
    for (int t4 = 0; t4 < 4; ++t4) {
      const int row = fq + t4 * 4;         // 0..15
      f32x4 g4 = *(const f32x4*)(ep + row * 68 + jw * 4);
      const float f_in = g4[0] + bi[0];
      const float i_in = g4[1] + bi[1];
      const float ic_in = g4[2] + bi[2];
      const float o_in = g4[3] + bi[3];
      const float ft = sigmoidf_(f_in);
      const float it = sigmoidf_(i_in);
      const float ics = __sinf(ic_in);
      const int mg = tm * 256 + wr * 128 + mi * 16 + row;
      const float cv = c[(size_t)mg * HDIM + jg];
      const float ct = cv * ft + ics * it;
      const float ot = sigmoidf_(o_in);
      const float ht = ot * __sinf(ct);
      out[(size_t)mg * HDIM + jg] = ht;
      out[OUT_HALF + (size_t)mg * HDIM + jg] = ct;
    }
    asm volatile("s_waitcnt lgkmcnt(0)" ::: "memory");
  }
}

extern "C" void kernel_launch(void* const* d_in, const int* in_sizes, int n_in,
                              void* d_out, int out_size, void* d_ws, size_t ws_size,
                              hipStream_t stream) {
  const float* x    = (const float*)d_in[0];
  const float* h    = (const float*)d_in[1];
  const float* c    = (const float*)d_in[2];
  const float* w_ih = (const float*)d_in[3];
  const float* w_hh = (const float*)d_in[4];
  const float* b_ih = (const float*)d_in[5];
  const float* b_hh = (const float*)d_in[6];
  float* out = (float*)d_out;

  char* ws = (char*)d_ws;
  unsigned short* Abf = (unsigned short*)ws;                       // 25,165,824 B
  unsigned short* Wbf = (unsigned short*)(ws + 25165824);          // 50,331,648 B
  float* bias = (float*)(ws + 25165824 + 50331648);                // 32,768 B

  hipFuncSetAttribute((const void*)lstm_gemm,
                      hipFuncAttributeMaxDynamicSharedMemorySize, 65536);

  // 6144 A-blocks + 3072 W-blocks
  pack_all<<<9216, 256, 0, stream>>>(x, h, w_ih, w_hh, b_ih, b_hh, Abf, Wbf, bias);
  lstm_gemm<<<512, 512, 65536, stream>>>(Abf, Wbf, bias, c, out);
}

// Round 16
// 220.426 us; speedup vs baseline: 1.0979x; 1.0979x over previous
//
#include <hip/hip_runtime.h>

typedef __attribute__((ext_vector_type(8))) short short8;
typedef __attribute__((ext_vector_type(4))) float f32x4;

// Problem dims
#define BDIM 4096
#define INDIM 1024
#define HDIM 2048
#define KDIM 3072   // IN + H
#define NDIM 8192   // 4*H
#define OUT_HALF 8388608  // 4096*2048
#define NKT 48      // K-tiles of 64
#define ACHUNKS 1572864

__device__ __forceinline__ unsigned short f2bf(float f) {
  unsigned u = __float_as_uint(f);
  u += 0x7FFFu + ((u >> 16) & 1u);
  return (unsigned short)(u >> 16);
}

__device__ __forceinline__ float sigmoidf_(float x) {
  return 1.0f / (1.0f + __expf(-x));
}

// Merged pack: A = [x|h] bf16 [4096][3072]; W' gate-interleaved bf16 [8192][3072];
// bias[n'] = b_ih + b_hh.
__global__ __launch_bounds__(256) void pack_all(
    const float* __restrict__ x, const float* __restrict__ hh,
    const float* __restrict__ w_ih, const float* __restrict__ w_hh,
    const float* __restrict__ b_ih, const float* __restrict__ b_hh,
    unsigned short* __restrict__ A, unsigned short* __restrict__ W,
    float* __restrict__ bias) {
  int idx = blockIdx.x * 256 + threadIdx.x;
  if (idx < ACHUNKS) {
    int m = idx / 384;
    int k0 = (idx - m * 384) * 8;
    const float* src = (k0 < INDIM) ? (x + (size_t)m * INDIM + k0)
                                    : (hh + (size_t)m * HDIM + (k0 - INDIM));
    float4 lo = ((const float4*)src)[0];
    float4 hi = ((const float4*)src)[1];
    union { unsigned short us[8]; uint4 v; } o;
    o.us[0] = f2bf(lo.x); o.us[1] = f2bf(lo.y); o.us[2] = f2bf(lo.z); o.us[3] = f2bf(lo.w);
    o.us[4] = f2bf(hi.x); o.us[5] = f2bf(hi.y); o.us[6] = f2bf(hi.z); o.us[7] = f2bf(hi.w);
    *(uint4*)(A + (size_t)m * KDIM + k0) = o.v;
  } else {
    idx -= ACHUNKS;
    int np = idx / 384;
    int rem = idx - np * 384;
    int k0 = rem * 8;
    int j = np >> 2;
    int g = np & 3;
    int n = g * HDIM + j;
    const float* src = (k0 < INDIM) ? (w_ih + (size_t)n * INDIM + k0)
                                    : (w_hh + (size_t)n * HDIM + (k0 - INDIM));
    float4 lo = ((const float4*)src)[0];
    float4 hi = ((const float4*)src)[1];
    union { unsigned short us[8]; uint4 v; } o;
    o.us[0] = f2bf(lo.x); o.us[1] = f2bf(lo.y); o.us[2] = f2bf(lo.z); o.us[3] = f2bf(lo.w);
    o.us[4] = f2bf(hi.x); o.us[5] = f2bf(hi.y); o.us[6] = f2bf(hi.z); o.us[7] = f2bf(hi.w);
    *(uint4*)(W + (size_t)np * KDIM + k0) = o.v;
    if (rem == 0) bias[np] = b_ih[n] + b_hh[n];
  }
}

__device__ __forceinline__ void gload_lds16(const void* g, void* l) {
  __builtin_amdgcn_global_load_lds(
      (const __attribute__((address_space(1))) void*)g,
      (__attribute__((address_space(3))) void*)l, 16, 0, 0);
}

#define SB0 __builtin_amdgcn_sched_barrier(0)

// 256x256 tile, BK=64, 8 waves (2Mx4N), ring-2 LDS (2 x 64KiB).
// ONE barrier per K-64 body (half of R10's sync events per K).
// Buffer: A[256][64]sw at +0 (32KB), B[256][64]sw at +32768.
// Swizzle: 16B chunk_phys = chunk_log ^ (row & 7) within each 128B row.
// 4 MFMA clusters of 16 per body; reads grouped so each cluster covers the
// next group's LDS latency. vmcnt(0)+lgkm0+barrier at body end (counted:
// only tile T+1's 8 stage loads outstanding, issued >=1500cy earlier).
__global__ __launch_bounds__(512, 2) void lstm_gemm(
    const unsigned short* __restrict__ A,
    const unsigned short* __restrict__ W,
    const float* __restrict__ bias,
    const float* __restrict__ c,
    float* __restrict__ out) {
  extern __shared__ char smem[];  // 131072 bytes

  const int tid = threadIdx.x;
  const int lane = tid & 63;
  const int wid = tid >> 6;

  // XCD swizzle: xcd owns 2 tm slabs; tn sweeps slowest. Bijective over 512.
  const int bid = blockIdx.x;
  const int local = bid >> 3;
  const int tm = (bid & 7) * 2 + (local & 1);   // 0..15
  const int tn = local >> 1;                    // 0..31

  // ---- staging source decode (inverse swizzle, rule #21) ----
  // Slot s dest P = s*8192 + tid*16: row = s*64 + (tid>>3),
  // chunk_log = (tid&7) ^ ((tid>>3)&7), src col = chunk_log*8.
  const int srowS = tid >> 3;
  const int clogS = (tid & 7) ^ (srowS & 7);
  const unsigned short* gA0 = A + (size_t)(tm * 256 +   0 + srowS) * KDIM + clogS * 8;
  const unsigned short* gA1 = A + (size_t)(tm * 256 +  64 + srowS) * KDIM + clogS * 8;
  const unsigned short* gA2 = A + (size_t)(tm * 256 + 128 + srowS) * KDIM + clogS * 8;
  const unsigned short* gA3 = A + (size_t)(tm * 256 + 192 + srowS) * KDIM + clogS * 8;
  const unsigned short* gB0 = W + (size_t)(tn * 256 +   0 + srowS) * KDIM + clogS * 8;
  const unsigned short* gB1 = W + (size_t)(tn * 256 +  64 + srowS) * KDIM + clogS * 8;
  const unsigned short* gB2 = W + (size_t)(tn * 256 + 128 + srowS) * KDIM + clogS * 8;
  const unsigned short* gB3 = W + (size_t)(tn * 256 + 192 + srowS) * KDIM + clogS * 8;
  const int ldT = tid * 16;   // + s*8192 (A); + 32768 + s*8192 (B)

  // ---- ds_read per-lane constants (swizzled) ----
  // Frag row = (wr*128 + mi*16 + fr); row&7 = fr&7. k-chunk log = ks*4+fq.
  const int fr = lane & 15;
  const int fq = lane >> 4;
  const int wr = wid >> 2;    // 0..1 (M half)
  const int wc = wid & 3;     // 0..3 (N quarter)
  const int cK0 = ((fq) ^ (fr & 7)) * 16;
  const int cK1 = ((4 + fq) ^ (fr & 7)) * 16;
  const int abase = wr * 16384 + fr * 128;            // + mi*2048 + cK
  const int bbase = 32768 + wc * 8192 + fr * 128;     // + ni*2048 + cK

  f32x4 acc[8][4] = {};
  short8 fa[4], ga[4], fb[4], gb[4];

#define STAGE_A(DB)                                   \
  do {                                                \
    gload_lds16(gA0, (DB) + 0 + ldT);                 \
    gload_lds16(gA1, (DB) + 8192 + ldT);              \
    gload_lds16(gA2, (DB) + 16384 + ldT);             \
    gload_lds16(gA3, (DB) + 24576 + ldT);             \
  } while (0)
#define STAGE_B(DB)                                   \
  do {                                                \
    gload_lds16(gB0, (DB) + 32768 + ldT);             \
    gload_lds16(gB1, (DB) + 40960 + ldT);             \
    gload_lds16(gB2, (DB) + 49152 + ldT);             \
    gload_lds16(gB3, (DB) + 57344 + ldT);             \
  } while (0)
#define ADV() do { gA0 += 64; gA1 += 64; gA2 += 64; gA3 += 64;               \
                   gB0 += 64; gB1 += 64; gB2 += 64; gB3 += 64; } while (0)
#define CLUST(AA, BB, MOFF)                                                  \
  do {                                                                       \
    __builtin_amdgcn_s_setprio(1);                                           \
    _Pragma("unroll")                                                        \
    for (int mi = 0; mi < 4; ++mi)                                           \
      _Pragma("unroll")                                                      \
      for (int ni = 0; ni < 4; ++ni)                                         \
        acc[mi + (MOFF)][ni] = __builtin_amdgcn_mfma_f32_16x16x32_bf16(      \
            AA[mi], BB[ni], acc[mi + (MOFF)][ni], 0, 0, 0);                  \
    __builtin_amdgcn_s_setprio(0);                                           \
  } while (0)

  // ---- prologue: stage tile 0 into buf0 ----
  STAGE_A(smem); STAGE_B(smem); ADV();
  asm volatile("s_waitcnt vmcnt(0)" ::: "memory");
  __builtin_amdgcn_s_barrier(); SB0;

#define BODY(T, STAGE_)                                                      \
  do {                                                                       \
    const char* rb = smem + ((T) & 1) * 65536;                               \
    char* nb = smem + ((~(T)) & 1) * 65536;                                  \
    if (STAGE_) STAGE_A(nb);                                                 \
    _Pragma("unroll")                                                        \
    for (int mi = 0; mi < 4; ++mi)                                           \
      fa[mi] = *(const short8*)(rb + abase + mi * 2048 + cK0);               \
    _Pragma("unroll")                                                        \
    for (int ni = 0; ni < 4; ++ni)                                           \
      fb[ni] = *(const short8*)(rb + bbase + ni * 2048 + cK0);               \
    _Pragma("unroll")                                                        \
    for (int mi = 0; mi < 4; ++mi)                                           \
      ga[mi] = *(const short8*)(rb + abase + (mi + 4) * 2048 + cK0);         \
    CLUST(fa, fb, 0);                                                        \
    _Pragma("unroll")                                                        \
    for (int mi = 0; mi < 4; ++mi)                                           \
      fa[mi] = *(const short8*)(rb + abase + mi * 2048 + cK1);               \
    _Pragma("unroll")                                                        \
    for (int ni = 0; ni < 4; ++ni)                                           \
      gb[ni] = *(const short8*)(rb + bbase + ni * 2048 + cK1);               \
    CLUST(ga, fb, 4);                                                        \
    if (STAGE_) { STAGE_B(nb); ADV(); }                                      \
    _Pragma("unroll")                                                        \
    for (int mi = 0; mi < 4; ++mi)                                           \
      ga[mi] = *(const short8*)(rb + abase + (mi + 4) * 2048 + cK1);         \
    CLUST(fa, gb, 0);                                                        \
    CLUST(ga, gb, 4);                                                        \
    SB0;                                                                     \
    asm volatile("s_waitcnt vmcnt(0) lgkmcnt(0)" ::: "memory");              \
    __builtin_amdgcn_s_barrier(); SB0;                                       \
  } while (0)

  for (int t = 0; t < NKT - 1; ++t) BODY(t, true);
  BODY(NKT - 1, false);
#undef BODY
#undef CLUST
#undef ADV
#undef STAGE_B
#undef STAGE_A

  // ---- fused LSTM epilogue ----
  // Wave-private LDS bounce, stride 68 floats (8 x 4608 = 36864 B, inside
  // buf0 whose tile-46 reads retired at body 46's lgkm0+barrier; body 47
  // read only buf1 and ended with a barrier).
  const int jw = fr;
  const int jg = tn * 64 + wc * 16 + jw;   // global j in [0,2048)
  const f32x4 bi = *(const f32x4*)(bias + tn * 256 + wc * 64 + jw * 4);
  float* ep = (float*)smem + wid * 1152;

#pragma unroll
  for (int mi = 0; mi < 8; ++mi) {
#pragma unroll
    for (int ni = 0; ni < 4; ++ni)
#pragma unroll
      for (int r = 0; r < 4; ++r)
        ep[(fq * 4 + r) * 68 + ni * 16 + fr] = acc[mi][ni][r];
    asm volatile("s_waitcnt lgkmcnt(0)" ::: "memory");
#pragma unroll
    for (int t4 = 0; t4 < 4; ++t4) {
      const int row = fq + t4 * 4;         // 0..15
      f32x4 g4 = *(const f32x4*)(ep + row * 68 + jw * 4);
      const float f_in = g4[0] + bi[0];
      const float i_in = g4[1] + bi[1];
      const float ic_in = g4[2] + bi[2];
      const float o_in = g4[3] + bi[3];
      const float ft = sigmoidf_(f_in);
      const float it = sigmoidf_(i_in);
      const float ics = __sinf(ic_in);
      const int mg = tm * 256 + wr * 128 + mi * 16 + row;
      const float cv = c[(size_t)mg * HDIM + jg];
      const float ct = cv * ft + ics * it;
      const float ot = sigmoidf_(o_in);
      const float ht = ot * __sinf(ct);
      out[(size_t)mg * HDIM + jg] = ht;
      out[OUT_HALF + (size_t)mg * HDIM + jg] = ct;
    }
    asm volatile("s_waitcnt lgkmcnt(0)" ::: "memory");
  }
}

extern "C" void kernel_launch(void* const* d_in, const int* in_sizes, int n_in,
                              void* d_out, int out_size, void* d_ws, size_t ws_size,
                              hipStream_t stream) {
  const float* x    = (const float*)d_in[0];
  const float* h    = (const float*)d_in[1];
  const float* c    = (const float*)d_in[2];
  const float* w_ih = (const float*)d_in[3];
  const float* w_hh = (const float*)d_in[4];
  const float* b_ih = (const float*)d_in[5];
  const float* b_hh = (const float*)d_in[6];
  float* out = (float*)d_out;

  char* ws = (char*)d_ws;
  unsigned short* Abf = (unsigned short*)ws;                       // 25,165,824 B
  unsigned short* Wbf = (unsigned short*)(ws + 25165824);          // 50,331,648 B
  float* bias = (float*)(ws + 25165824 + 50331648);                // 32,768 B

  hipFuncSetAttribute((const void*)lstm_gemm,
                      hipFuncAttributeMaxDynamicSharedMemorySize, 131072);

  pack_all<<<18432, 256, 0, stream>>>(x, h, w_ih, w_hh, b_ih, b_hh, Abf, Wbf, bias);
  lstm_gemm<<<512, 512, 131072, stream>>>(Abf, Wbf, bias, c, out);
}

// Round 17
// 219.437 us; speedup vs baseline: 1.1029x; 1.0045x over previous
//
#include <hip/hip_runtime.h>

typedef __attribute__((ext_vector_type(8))) short short8;
typedef __attribute__((ext_vector_type(4))) float f32x4;

// Problem dims
#define BDIM 4096
#define INDIM 1024
#define HDIM 2048
#define KDIM 3072   // IN + H
#define NDIM 8192   // 4*H
#define OUT_HALF 8388608  // 4096*2048
#define NKT 96      // K-tiles of 32
#define ACHUNKS 1572864

__device__ __forceinline__ unsigned short f2bf(float f) {
  unsigned u = __float_as_uint(f);
  u += 0x7FFFu + ((u >> 16) & 1u);
  return (unsigned short)(u >> 16);
}

__device__ __forceinline__ float sigmoidf_(float x) {
  return 1.0f / (1.0f + __expf(-x));
}

// Merged pack: A = [x|h] bf16 [4096][3072]; W' gate-interleaved bf16 [8192][3072];
// bias[n'] = b_ih + b_hh.
__global__ __launch_bounds__(256) void pack_all(
    const float* __restrict__ x, const float* __restrict__ hh,
    const float* __restrict__ w_ih, const float* __restrict__ w_hh,
    const float* __restrict__ b_ih, const float* __restrict__ b_hh,
    unsigned short* __restrict__ A, unsigned short* __restrict__ W,
    float* __restrict__ bias) {
  int idx = blockIdx.x * 256 + threadIdx.x;
  if (idx < ACHUNKS) {
    int m = idx / 384;
    int k0 = (idx - m * 384) * 8;
    const float* src = (k0 < INDIM) ? (x + (size_t)m * INDIM + k0)
                                    : (hh + (size_t)m * HDIM + (k0 - INDIM));
    float4 lo = ((const float4*)src)[0];
    float4 hi = ((const float4*)src)[1];
    union { unsigned short us[8]; uint4 v; } o;
    o.us[0] = f2bf(lo.x); o.us[1] = f2bf(lo.y); o.us[2] = f2bf(lo.z); o.us[3] = f2bf(lo.w);
    o.us[4] = f2bf(hi.x); o.us[5] = f2bf(hi.y); o.us[6] = f2bf(hi.z); o.us[7] = f2bf(hi.w);
    *(uint4*)(A + (size_t)m * KDIM + k0) = o.v;
  } else {
    idx -= ACHUNKS;
    int np = idx / 384;
    int rem = idx - np * 384;
    int k0 = rem * 8;
    int j = np >> 2;
    int g = np & 3;
    int n = g * HDIM + j;
    const float* src = (k0 < INDIM) ? (w_ih + (size_t)n * INDIM + k0)
                                    : (w_hh + (size_t)n * HDIM + (k0 - INDIM));
    float4 lo = ((const float4*)src)[0];
    float4 hi = ((const float4*)src)[1];
    union { unsigned short us[8]; uint4 v; } o;
    o.us[0] = f2bf(lo.x); o.us[1] = f2bf(lo.y); o.us[2] = f2bf(lo.z); o.us[3] = f2bf(lo.w);
    o.us[4] = f2bf(hi.x); o.us[5] = f2bf(hi.y); o.us[6] = f2bf(hi.z); o.us[7] = f2bf(hi.w);
    *(uint4*)(W + (size_t)np * KDIM + k0) = o.v;
    if (rem == 0) bias[np] = b_ih[n] + b_hh[n];
  }
}

__device__ __forceinline__ void gload_lds16(const void* g, void* l) {
  __builtin_amdgcn_global_load_lds(
      (const __attribute__((address_space(1))) void*)g,
      (__attribute__((address_space(3))) void*)l, 16, 0, 0);
}

#define SB0 __builtin_amdgcn_sched_barrier(0)

// 256x256 tile, BK=32, 8 waves (2Mx4N), 5-deep LDS ring (5 x 32KiB = 160KB),
// row-pair XOR swizzle (T2), setprio (T5). R10 body, but BARRIER ONLY EVERY
// 2nd BODY: within a pair, waves slip (per-wave compiler waits only), so one
// wave's MFMA overlaps another's ds-reads (de-alternates LDS/matrix pipes).
// Pair barrier: vmcnt(4)+lgkm0 certify next pair's two tiles landed (stage
// distance 3; stages never target the 3 bufs being read in the pair).
__global__ __launch_bounds__(512, 2) void lstm_gemm(
    const unsigned short* __restrict__ A,
    const unsigned short* __restrict__ W,
    const float* __restrict__ bias,
    const float* __restrict__ c,
    float* __restrict__ out) {
  extern __shared__ char smem[];  // 163840 bytes

  const int tid = threadIdx.x;
  const int lane = tid & 63;
  const int wid = tid >> 6;

  // XCD swizzle: xcd owns 2 tm slabs; tn sweeps slowest. Bijective over 512.
  const int bid = blockIdx.x;
  const int local = bid >> 3;
  const int tm = (bid & 7) * 2 + (local & 1);   // 0..15
  const int tn = local >> 1;                    // 0..31

  // ---- staging source decode (inverse swizzle, rule #21; R10-identical) ----
  int rowA0, clA0, rowA1, clA1;
  {
    int P0 = wid * 1024 + lane * 16;
    int P1 = 8192 + wid * 1024 + lane * 16;
    int r2, cp, cg;
    r2 = P0 >> 7; cp = (P0 >> 4) & 7; cg = cp ^ (r2 & 7);
    rowA0 = r2 * 2 + (cg >> 2); clA0 = cg & 3;
    r2 = P1 >> 7; cp = (P1 >> 4) & 7; cg = cp ^ (r2 & 7);
    rowA1 = r2 * 2 + (cg >> 2); clA1 = cg & 3;
  }
  const unsigned short* gA0 = A + (size_t)(tm * 256 + rowA0) * KDIM + clA0 * 8;
  const unsigned short* gA1 = A + (size_t)(tm * 256 + rowA1) * KDIM + clA1 * 8;
  const unsigned short* gB0 = W + (size_t)(tn * 256 + rowA0) * KDIM + clA0 * 8;
  const unsigned short* gB1 = W + (size_t)(tn * 256 + rowA1) * KDIM + clA1 * 8;
  const int ldA0 = wid * 1024;
  const int ldA1 = 8192 + wid * 1024;
  const int ldB0 = 16384 + wid * 1024;
  const int ldB1 = 24576 + wid * 1024;

  // ---- ds_read per-lane constants (swizzled) ----
  const int fr = lane & 15;
  const int fq = lane >> 4;
  const int wr = wid >> 2;    // 0..1 (rows)
  const int wc = wid & 3;     // 0..3 (cols)
  const int frh = fr >> 1;
  const int clA = (((fr & 1) << 2) | fq) ^ frh;
  const int aconst = wr * 8192 + frh * 128 + clA * 16;
  const int bconst = 16384 + wc * 4096 + frh * 128 + clA * 16;

  f32x4 acc[8][4] = {};
  short8 af[4], bf_[4], ag[4];

  char* const b0 = smem;
  char* const b1 = smem + 32768;
  char* const b2 = smem + 65536;
  char* const b3 = smem + 98304;
  char* const b4 = smem + 131072;

#define STAGE_A(LB) do { gload_lds16(gA0, (LB) + ldA0);                      \
                         gload_lds16(gA1, (LB) + ldA1); } while (0)
#define STAGE_B(LB) do { gload_lds16(gB0, (LB) + ldB0);                      \
                         gload_lds16(gB1, (LB) + ldB1);                      \
                         gA0 += 32; gA1 += 32; gB0 += 32; gB1 += 32; } while (0)

  // ---- prologue: stage tiles 0,1,2 into b0,b1,b2 ----
  STAGE_A(b0); STAGE_B(b0);
  STAGE_A(b1); STAGE_B(b1);
  STAGE_A(b2); STAGE_B(b2);
  asm volatile("s_waitcnt vmcnt(4)" ::: "memory");   // tiles 0,1 landed
  __builtin_amdgcn_s_barrier(); SB0;
#pragma unroll
  for (int mi = 0; mi < 4; ++mi)
    af[mi] = *(const short8*)(b0 + aconst + mi * 1024);
#pragma unroll
  for (int ni = 0; ni < 4; ++ni)
    bf_[ni] = *(const short8*)(b0 + bconst + ni * 1024);

#define MFMA_A()                                                             \
  do {                                                                       \
    __builtin_amdgcn_s_setprio(1);                                           \
    _Pragma("unroll")                                                        \
    for (int mi = 0; mi < 4; ++mi)                                           \
      _Pragma("unroll")                                                      \
      for (int ni = 0; ni < 4; ++ni)                                         \
        acc[mi][ni] = __builtin_amdgcn_mfma_f32_16x16x32_bf16(               \
            af[mi], bf_[ni], acc[mi][ni], 0, 0, 0);                          \
    __builtin_amdgcn_s_setprio(0);                                           \
  } while (0)
#define MFMA_B()                                                             \
  do {                                                                       \
    __builtin_amdgcn_s_setprio(1);                                           \
    _Pragma("unroll")                                                        \
    for (int mi = 0; mi < 4; ++mi)                                           \
      _Pragma("unroll")                                                      \
      for (int ni = 0; ni < 4; ++ni)                                         \
        acc[mi + 4][ni] = __builtin_amdgcn_mfma_f32_16x16x32_bf16(           \
            ag[mi], bf_[ni], acc[mi + 4][ni], 0, 0, 0);                      \
    __builtin_amdgcn_s_setprio(0);                                           \
  } while (0)
#define READ_AG(RB)                                                          \
  _Pragma("unroll")                                                          \
  for (int mi = 0; mi < 4; ++mi)                                             \
    ag[mi] = *(const short8*)((RB) + aconst + (mi + 4) * 1024);
#define READ_AF(RBN)                                                         \
  _Pragma("unroll")                                                          \
  for (int mi = 0; mi < 4; ++mi)                                             \
    af[mi] = *(const short8*)((RBN) + aconst + mi * 1024);
#define READ_BF(RBN)                                                         \
  _Pragma("unroll")                                                          \
  for (int ni = 0; ni < 4; ++ni)                                             \
    bf_[ni] = *(const short8*)((RBN) + bconst + ni * 1024);

// Pair of bodies (T even, T+1 odd). BA=buf[T%5] BB=buf[(T+1)%5]
// BC=buf[(T+2)%5] BD=buf[(T+3)%5] BE=buf[(T+4)%5].
// Even body: NO barrier (per-wave compiler waits only). Odd body: counted
// vmcnt + lgkm0 + barrier before its af/bf prefetch (next pair certified).
#define PAIRX(BA, BB, BC, BD, BE, STGE, STGO, VMSTR, PREF)                   \
  do {                                                                       \
    /* even body: reads tile T from BA, prefetch T+1 from BB (certified) */  \
    if (STGE) STAGE_A(BD);                                                   \
    READ_AG(BA); SB0;                                                        \
    MFMA_A();                                                                \
    if (STGE) STAGE_B(BD);                                                   \
    READ_AF(BB);                                                             \
    MFMA_B();                                                                \
    READ_BF(BB);                                                             \
    /* odd body: reads tile T+1 from BB, prefetch T+2 from BC (certified     \
       at the barrier below) */                                              \
    if (STGO) STAGE_A(BE);                                                   \
    READ_AG(BB); SB0;                                                        \
    MFMA_A();                                                                \
    if (STGO) STAGE_B(BE);                                                   \
    asm volatile("s_waitcnt vmcnt(" VMSTR ")" ::: "memory");                 \
    asm volatile("s_waitcnt lgkmcnt(0)" ::: "memory");                       \
    __builtin_amdgcn_s_barrier(); SB0;                                       \
    if (PREF) { READ_AF(BC); }                                               \
    SB0;                                                                     \
    MFMA_B();                                                                \
    if (PREF) { READ_BF(BC); }                                               \
  } while (0)

  for (int t = 0; t < 90; t += 10) {
    PAIRX(b0, b1, b2, b3, b4, true, true, "4", true);
    PAIRX(b2, b3, b4, b0, b1, true, true, "4", true);
    PAIRX(b4, b0, b1, b2, b3, true, true, "4", true);
    PAIRX(b1, b2, b3, b4, b0, true, true, "4", true);
    PAIRX(b3, b4, b0, b1, b2, true, true, "4", true);
  }
  PAIRX(b0, b1, b2, b3, b4, true,  true,  "4", true);   // bodies 90,91
  PAIRX(b2, b3, b4, b0, b1, true,  false, "0", true);   // bodies 92,93
  PAIRX(b4, b0, b1, b2, b3, false, false, "0", false);  // bodies 94,95
#undef PAIRX
#undef READ_BF
#undef READ_AF
#undef READ_AG
#undef MFMA_B
#undef MFMA_A
#undef STAGE_B
#undef STAGE_A

  // ---- fused LSTM epilogue ----
  // Wave-private LDS bounce, stride 68 floats (8 x 4608 = 36864 B, in b0/b1).
  // Safe: final pair's barrier (inside body 95) came after lgkm0 of ALL
  // reads; post-barrier ops are register-only (MFMA_B, no PREF).
  const int jw = fr;
  const int jg = tn * 64 + wc * 16 + jw;   // global j in [0,2048)
  const f32x4 bi = *(const f32x4*)(bias + tn * 256 + wc * 64 + jw * 4);
  float* ep = (float*)smem + wid * 1152;

#pragma unroll
  for (int mi = 0; mi < 8; ++mi) {
#pragma unroll
    for (int ni = 0; ni < 4; ++ni)
#pragma unroll
      for (int r = 0; r < 4; ++r)
        ep[(fq * 4 + r) * 68 + ni * 16 + fr] = acc[mi][ni][r];
    asm volatile("s_waitcnt lgkmcnt(0)" ::: "memory");
#pragma unroll
    for (int t4 = 0; t4 < 4; ++t4) {
      const int row = fq + t4 * 4;         // 0..15
      f32x4 g4 = *(const f32x4*)(ep + row * 68 + jw * 4);
      const float f_in = g4[0] + bi[0];
      const float i_in = g4[1] + bi[1];
      const float ic_in = g4[2] + bi[2];
      const float o_in = g4[3] + bi[3];
      const float ft = sigmoidf_(f_in);
      const float it = sigmoidf_(i_in);
      const float ics = __sinf(ic_in);
      const int mg = tm * 256 + wr * 128 + mi * 16 + row;
      const float cv = c[(size_t)mg * HDIM + jg];
      const float ct = cv * ft + ics * it;
      const float ot = sigmoidf_(o_in);
      const float ht = ot * __sinf(ct);
      out[(size_t)mg * HDIM + jg] = ht;
      out[OUT_HALF + (size_t)mg * HDIM + jg] = ct;
    }
    asm volatile("s_waitcnt lgkmcnt(0)" ::: "memory");
  }
}

extern "C" void kernel_launch(void* const* d_in, const int* in_sizes, int n_in,
                              void* d_out, int out_size, void* d_ws, size_t ws_size,
                              hipStream_t stream) {
  const float* x    = (const float*)d_in[0];
  const float* h    = (const float*)d_in[1];
  const float* c    = (const float*)d_in[2];
  const float* w_ih = (const float*)d_in[3];
  const float* w_hh = (const float*)d_in[4];
  const float* b_ih = (const float*)d_in[5];
  const float* b_hh = (const float*)d_in[6];
  float* out = (float*)d_out;

  char* ws = (char*)d_ws;
  unsigned short* Abf = (unsigned short*)ws;                       // 25,165,824 B
  unsigned short* Wbf = (unsigned short*)(ws + 25165824);          // 50,331,648 B
  float* bias = (float*)(ws + 25165824 + 50331648);                // 32,768 B

  hipFuncSetAttribute((const void*)lstm_gemm,
                      hipFuncAttributeMaxDynamicSharedMemorySize, 163840);

  pack_all<<<18432, 256, 0, stream>>>(x, h, w_ih, w_hh, b_ih, b_hh, Abf, Wbf, bias);
  lstm_gemm<<<512, 512, 163840, stream>>>(Abf, Wbf, bias, c, out);
}

// Round 18
// 217.728 us; speedup vs baseline: 1.1115x; 1.0078x over previous
//
#include <hip/hip_runtime.h>

typedef __attribute__((ext_vector_type(8))) short short8;
typedef __attribute__((ext_vector_type(4))) float f32x4;

// Problem dims
#define BDIM 4096
#define INDIM 1024
#define HDIM 2048
#define KDIM 3072   // IN + H
#define NDIM 8192   // 4*H
#define OUT_HALF 8388608  // 4096*2048
#define NKT 96      // K-tiles of 32
#define ACHUNKS 1572864

__device__ __forceinline__ unsigned short f2bf(float f) {
  unsigned u = __float_as_uint(f);
  u += 0x7FFFu + ((u >> 16) & 1u);
  return (unsigned short)(u >> 16);
}

__device__ __forceinline__ float sigmoidf_(float x) {
  return 1.0f / (1.0f + __expf(-x));
}

// Merged pack: A = [x|h] bf16 [4096][3072]; W' gate-interleaved bf16 [8192][3072];
// bias[n'] = b_ih + b_hh.
__global__ __launch_bounds__(256) void pack_all(
    const float* __restrict__ x, const float* __restrict__ hh,
    const float* __restrict__ w_ih, const float* __restrict__ w_hh,
    const float* __restrict__ b_ih, const float* __restrict__ b_hh,
    unsigned short* __restrict__ A, unsigned short* __restrict__ W,
    float* __restrict__ bias) {
  int idx = blockIdx.x * 256 + threadIdx.x;
  if (idx < ACHUNKS) {
    int m = idx / 384;
    int k0 = (idx - m * 384) * 8;
    const float* src = (k0 < INDIM) ? (x + (size_t)m * INDIM + k0)
                                    : (hh + (size_t)m * HDIM + (k0 - INDIM));
    float4 lo = ((const float4*)src)[0];
    float4 hi = ((const float4*)src)[1];
    union { unsigned short us[8]; uint4 v; } o;
    o.us[0] = f2bf(lo.x); o.us[1] = f2bf(lo.y); o.us[2] = f2bf(lo.z); o.us[3] = f2bf(lo.w);
    o.us[4] = f2bf(hi.x); o.us[5] = f2bf(hi.y); o.us[6] = f2bf(hi.z); o.us[7] = f2bf(hi.w);
    *(uint4*)(A + (size_t)m * KDIM + k0) = o.v;
  } else {
    idx -= ACHUNKS;
    int np = idx / 384;
    int rem = idx - np * 384;
    int k0 = rem * 8;
    int j = np >> 2;
    int g = np & 3;
    int n = g * HDIM + j;
    const float* src = (k0 < INDIM) ? (w_ih + (size_t)n * INDIM + k0)
                                    : (w_hh + (size_t)n * HDIM + (k0 - INDIM));
    float4 lo = ((const float4*)src)[0];
    float4 hi = ((const float4*)src)[1];
    union { unsigned short us[8]; uint4 v; } o;
    o.us[0] = f2bf(lo.x); o.us[1] = f2bf(lo.y); o.us[2] = f2bf(lo.z); o.us[3] = f2bf(lo.w);
    o.us[4] = f2bf(hi.x); o.us[5] = f2bf(hi.y); o.us[6] = f2bf(hi.z); o.us[7] = f2bf(hi.w);
    *(uint4*)(W + (size_t)np * KDIM + k0) = o.v;
    if (rem == 0) bias[np] = b_ih[n] + b_hh[n];
  }
}

__device__ __forceinline__ void gload_lds16(const void* g, void* l) {
  __builtin_amdgcn_global_load_lds(
      (const __attribute__((address_space(1))) void*)g,
      (__attribute__((address_space(3))) void*)l, 16, 0, 0);
}

#define SB0 __builtin_amdgcn_sched_barrier(0)

// R10-exact GEMM K-loop (best of 12 measured structures): 256x256 tile,
// BK=32, 8 waves (2Mx4N), 4-deep LDS ring (4 x 32KiB), row-pair XOR swizzle
// (T2), counted vmcnt (T4), setprio (T5), 1-barrier-per-K-tile pipelined
// schedule. Epilogue vectorized: lane = (row, j-quad) so c-loads and ht/ct
// stores are f32x4 (-9 instr/lane/mi, same transactions).
__global__ __launch_bounds__(512, 2) void lstm_gemm(
    const unsigned short* __restrict__ A,
    const unsigned short* __restrict__ W,
    const float* __restrict__ bias,
    const float* __restrict__ c,
    float* __restrict__ out) {
  extern __shared__ char smem[];  // 131072 bytes

  const int tid = threadIdx.x;
  const int lane = tid & 63;
  const int wid = tid >> 6;

  // XCD swizzle: xcd owns 2 tm slabs; tn sweeps slowest. Bijective over 512.
  const int bid = blockIdx.x;
  const int local = bid >> 3;
  const int tm = (bid & 7) * 2 + (local & 1);   // 0..15
  const int tn = local >> 1;                    // 0..31

  // ---- staging source decode (inverse swizzle, rule #21) ----
  int rowA0, clA0, rowA1, clA1;
  {
    int P0 = wid * 1024 + lane * 16;
    int P1 = 8192 + wid * 1024 + lane * 16;
    int r2, cp, cg;
    r2 = P0 >> 7; cp = (P0 >> 4) & 7; cg = cp ^ (r2 & 7);
    rowA0 = r2 * 2 + (cg >> 2); clA0 = cg & 3;
    r2 = P1 >> 7; cp = (P1 >> 4) & 7; cg = cp ^ (r2 & 7);
    rowA1 = r2 * 2 + (cg >> 2); clA1 = cg & 3;
  }
  const unsigned short* gA0 = A + (size_t)(tm * 256 + rowA0) * KDIM + clA0 * 8;
  const unsigned short* gA1 = A + (size_t)(tm * 256 + rowA1) * KDIM + clA1 * 8;
  const unsigned short* gB0 = W + (size_t)(tn * 256 + rowA0) * KDIM + clA0 * 8;
  const unsigned short* gB1 = W + (size_t)(tn * 256 + rowA1) * KDIM + clA1 * 8;
  const int ldA0 = wid * 1024;
  const int ldA1 = 8192 + wid * 1024;
  const int ldB0 = 16384 + wid * 1024;
  const int ldB1 = 24576 + wid * 1024;

  // ---- ds_read per-lane constants (swizzled) ----
  const int fr = lane & 15;
  const int fq = lane >> 4;
  const int wr = wid >> 2;    // 0..1 (rows)
  const int wc = wid & 3;     // 0..3 (cols)
  const int frh = fr >> 1;
  const int clA = (((fr & 1) << 2) | fq) ^ frh;
  const int aconst = wr * 8192 + frh * 128 + clA * 16;
  const int bconst = 16384 + wc * 4096 + frh * 128 + clA * 16;

  f32x4 acc[8][4] = {};
  short8 af[4], bf_[4], ag[4];

  // ---- prologue: stage tiles 0,1,2 ----
#pragma unroll
  for (int tt = 0; tt < 3; ++tt) {
    char* lb = smem + tt * 32768;
    gload_lds16(gA0, lb + ldA0);
    gload_lds16(gA1, lb + ldA1);
    gload_lds16(gB0, lb + ldB0);
    gload_lds16(gB1, lb + ldB1);
    gA0 += 32; gA1 += 32; gB0 += 32; gB1 += 32;
  }
  asm volatile("s_waitcnt vmcnt(8)" ::: "memory");   // tile 0 landed
  __builtin_amdgcn_s_barrier(); SB0;
  // issue af(0), bf_(0)
#pragma unroll
  for (int mi = 0; mi < 4; ++mi)
    af[mi] = *(const short8*)(smem + aconst + mi * 1024);
#pragma unroll
  for (int ni = 0; ni < 4; ++ni)
    bf_[ni] = *(const short8*)(smem + bconst + ni * 1024);

// Tile body. Entry: af(T),bf_(T) issued; vm queue = stages for T+1,T+2 (8).
#define TILE_BODY(T, VMSTR, STAGE_, PREF_)                                   \
  do {                                                                       \
    const char* rb = smem + ((T) & 3) * 32768;                               \
    const char* rbn = smem + (((T) + 1) & 3) * 32768;                        \
    char* lb = smem + (((T) + 3) & 3) * 32768;                               \
    if (STAGE_) {                                                            \
      gload_lds16(gA0, lb + ldA0);                                           \
      gload_lds16(gA1, lb + ldA1);                                           \
    }                                                                        \
    _Pragma("unroll")                                                        \
    for (int mi = 0; mi < 4; ++mi)                                           \
      ag[mi] = *(const short8*)(rb + aconst + (mi + 4) * 1024);              \
    SB0;                                                                     \
    __builtin_amdgcn_s_setprio(1);                                           \
    _Pragma("unroll")                                                        \
    for (int mi = 0; mi < 4; ++mi)                                           \
      _Pragma("unroll")                                                      \
      for (int ni = 0; ni < 4; ++ni)                                         \
        acc[mi][ni] = __builtin_amdgcn_mfma_f32_16x16x32_bf16(               \
            af[mi], bf_[ni], acc[mi][ni], 0, 0, 0);                          \
    __builtin_amdgcn_s_setprio(0);                                           \
    if (STAGE_) {                                                            \
      gload_lds16(gB0, lb + ldB0);                                           \
      gload_lds16(gB1, lb + ldB1);                                           \
      gA0 += 32; gA1 += 32; gB0 += 32; gB1 += 32;                            \
    }                                                                        \
    asm volatile("s_waitcnt vmcnt(" VMSTR ")" ::: "memory");                 \
    asm volatile("s_waitcnt lgkmcnt(0)" ::: "memory");                       \
    __builtin_amdgcn_s_barrier(); SB0;                                       \
    if (PREF_) {                                                             \
      _Pragma("unroll")                                                      \
      for (int mi = 0; mi < 4; ++mi)                                         \
        af[mi] = *(const short8*)(rbn + aconst + mi * 1024);                 \
    }                                                                        \
    SB0;                                                                     \
    __builtin_amdgcn_s_setprio(1);                                           \
    _Pragma("unroll")                                                        \
    for (int mi = 0; mi < 4; ++mi)                                           \
      _Pragma("unroll")                                                      \
      for (int ni = 0; ni < 4; ++ni)                                         \
        acc[mi + 4][ni] = __builtin_amdgcn_mfma_f32_16x16x32_bf16(           \
            ag[mi], bf_[ni], acc[mi + 4][ni], 0, 0, 0);                      \
    __builtin_amdgcn_s_setprio(0);                                           \
    if (PREF_) {                                                             \
      _Pragma("unroll")                                                      \
      for (int ni = 0; ni < 4; ++ni)                                         \
        bf_[ni] = *(const short8*)(rbn + bconst + ni * 1024);                \
    }                                                                        \
  } while (0)

  for (int t = 0; t < NKT - 3; ++t) TILE_BODY(t, "8", true, true);
  TILE_BODY(NKT - 3, "4", false, true);
  TILE_BODY(NKT - 2, "0", false, true);
  TILE_BODY(NKT - 1, "0", false, false);
#undef TILE_BODY

  // ---- fused LSTM epilogue (vectorized consumer) ----
  // Writes keep the (fq,fr) C-layout mapping; consumer lane = (rsel =
  // lane>>2 row, jsel = lane&3 j-quad): 4x f32x4 ep reads (64B/lane,
  // 2-way-bank free), 1x f32x4 c-load, 2x f32x4 stores.
  const int rsel = lane >> 2;
  const int jsel = lane & 3;
  const int jgb = tn * 64 + wc * 16 + jsel * 4;   // first of 4 global j
  f32x4 bi4[4];
#pragma unroll
  for (int q = 0; q < 4; ++q)
    bi4[q] = *(const f32x4*)(bias + tn * 256 + wc * 64 + (jsel * 4 + q) * 4);
  float* ep = (float*)smem + wid * 1152;

#pragma unroll
  for (int mi = 0; mi < 8; ++mi) {
#pragma unroll
    for (int ni = 0; ni < 4; ++ni)
#pragma unroll
      for (int r = 0; r < 4; ++r)
        ep[(fq * 4 + r) * 68 + ni * 16 + fr] = acc[mi][ni][r];
    asm volatile("s_waitcnt lgkmcnt(0)" ::: "memory");
    const int mg = tm * 256 + wr * 128 + mi * 16 + rsel;
    f32x4 g[4];
#pragma unroll
    for (int q = 0; q < 4; ++q)
      g[q] = *(const f32x4*)(ep + rsel * 68 + (jsel * 4 + q) * 4);
    const f32x4 cv = *(const f32x4*)(c + (size_t)mg * HDIM + jgb);
    f32x4 ht4, ct4;
#pragma unroll
    for (int q = 0; q < 4; ++q) {
      const float f_in = g[q][0] + bi4[q][0];
      const float i_in = g[q][1] + bi4[q][1];
      const float ic_in = g[q][2] + bi4[q][2];
      const float o_in = g[q][3] + bi4[q][3];
      const float ft = sigmoidf_(f_in);
      const float it = sigmoidf_(i_in);
      const float ics = __sinf(ic_in);
      const float ct = cv[q] * ft + ics * it;
      const float ot = sigmoidf_(o_in);
      ht4[q] = ot * __sinf(ct);
      ct4[q] = ct;
    }
    *(f32x4*)(out + (size_t)mg * HDIM + jgb) = ht4;
    *(f32x4*)(out + OUT_HALF + (size_t)mg * HDIM + jgb) = ct4;
    asm volatile("s_waitcnt lgkmcnt(0)" ::: "memory");
  }
}

extern "C" void kernel_launch(void* const* d_in, const int* in_sizes, int n_in,
                              void* d_out, int out_size, void* d_ws, size_t ws_size,
                              hipStream_t stream) {
  const float* x    = (const float*)d_in[0];
  const float* h    = (const float*)d_in[1];
  const float* c    = (const float*)d_in[2];
  const float* w_ih = (const float*)d_in[3];
  const float* w_hh = (const float*)d_in[4];
  const float* b_ih = (const float*)d_in[5];
  const float* b_hh = (const float*)d_in[6];
  float* out = (float*)d_out;

  char* ws = (char*)d_ws;
  unsigned short* Abf = (unsigned short*)ws;                       // 25,165,824 B
  unsigned short* Wbf = (unsigned short*)(ws + 25165824);          // 50,331,648 B
  float* bias = (float*)(ws + 25165824 + 50331648);                // 32,768 B

  hipFuncSetAttribute((const void*)lstm_gemm,
                      hipFuncAttributeMaxDynamicSharedMemorySize, 131072);

  pack_all<<<18432, 256, 0, stream>>>(x, h, w_ih, w_hh, b_ih, b_hh, Abf, Wbf, bias);
  lstm_gemm<<<512, 512, 131072, stream>>>(Abf, Wbf, bias, c, out);
}